// Round 1
// baseline (209.703 us; speedup 1.0000x reference)
//
#include <hip/hip_runtime.h>

#define BB 4
#define AA 100000
#define MM 32
#define NC 80
#define GX 391               // ceil(AA/256)
#define NBLK (GX * BB)       // 1564 blocks

// ws layout (floats): cls_part[NBLK] | reg_part[NBLK] | pos_part[NBLK] (as uint)
// All partials written unconditionally by every block -> no zero-init, no atomics.

// ---- focal math for one float4 (4 classes), arithmetic identical to baseline ----
// pc[] runtime-index replaced with explicit select tree (no scratch hazard).
#define FOCAL_K(vk, flatk)                                                  \
  {                                                                         \
    const int s    = (flatk) / 20;                                          \
    const int colb = ((flatk) - s * 20) * 4;                                \
    const int c    = scode[s];                                              \
    const float m  = (c != -2) ? 1.0f : 0.0f;                               \
    const float q0 = fminf(fmaxf((vk).x, 1e-4f), 0.9999f);                  \
    const float q1 = fminf(fmaxf((vk).y, 1e-4f), 0.9999f);                  \
    const float q2 = fminf(fmaxf((vk).z, 1e-4f), 0.9999f);                  \
    const float q3 = fminf(fmaxf((vk).w, 1e-4f), 0.9999f);                  \
    float sub = 0.0f;                                                       \
    sub += 0.75f * q0 * q0 * (-__logf(1.0f - q0));                          \
    sub += 0.75f * q1 * q1 * (-__logf(1.0f - q1));                          \
    sub += 0.75f * q2 * q2 * (-__logf(1.0f - q2));                          \
    sub += 0.75f * q3 * q3 * (-__logf(1.0f - q3));                          \
    csum += m * sub;                                                        \
    const unsigned rel = (unsigned)(c - colb);                              \
    if (rel < 4u) {  /* rare: the labeled column lands in this float4 */    \
      const float p = (rel & 2u) ? ((rel & 1u) ? q3 : q2)                   \
                                 : ((rel & 1u) ? q1 : q0);                  \
      const float onem = 1.0f - p;                                          \
      csum += 0.25f * onem * onem * (-__logf(p))                            \
            - 0.75f * p * p * (-__logf(onem));                              \
    }                                                                       \
  }

#define FOCAL_BATCH(vv, batch)                                              \
  _Pragma("unroll")                                                         \
  for (int k = 0; k < 5; ++k) {                                             \
    const int flat = ((batch) * 5 + k) * 256 + tid;                         \
    FOCAL_K((vv)[k], flat)                                                  \
  }

__global__ __launch_bounds__(256, 4) void fused_kernel(
    const float* __restrict__ anchors,      // AA*4
    const float* __restrict__ annotations,  // BB*MM*5
    const float* __restrict__ regression,   // BB*AA*4
    const float* __restrict__ cls,          // BB*AA*NC, read as float4
    float* __restrict__ cls_part,
    float* __restrict__ reg_part,
    unsigned* __restrict__ pos_part)
{
    __shared__ float ann[MM * 5];
    __shared__ float areab[MM];
    __shared__ int scode[256];   // -2 = excluded/fake, -1 = valid negative, 0..79 = positive class
    const int b = blockIdx.y;
    const int tid = threadIdx.x;
    if (tid < MM * 5) ann[tid] = annotations[b * MM * 5 + tid];
    if (tid < MM) {
        // same __fsub_rn/__fmul_rn ops as the per-anchor version -> identical bits
        const float bx1 = annotations[b * MM * 5 + tid * 5 + 0];
        const float by1 = annotations[b * MM * 5 + tid * 5 + 1];
        const float bx2 = annotations[b * MM * 5 + tid * 5 + 2];
        const float by2 = annotations[b * MM * 5 + tid * 5 + 3];
        areab[tid] = __fmul_rn(__fsub_rn(bx2, bx1), __fsub_rn(by2, by1));
    }
    __syncthreads();

    const int abase = blockIdx.x * 256;
    const int a = abase + tid;

    // ---- prefetch: batches 0 and 1 of the focal stream are issued BEFORE the
    // IoU phase. Their addresses are affine in (block, tid) — nothing
    // data-dependent — so their ~HBM latency and the stream ramp-up hide under
    // the compute-only IoU loop instead of leaving HBM idle for its duration.
    const float4* base4 = (const float4*)cls + ((size_t)b * AA + abase) * 20;
    const int maxflat = (abase + 256 <= AA) ? (5120 - 1) : ((AA - abase) * 20 - 1);

    float4 vA[5], vB[5];
    #pragma unroll
    for (int k = 0; k < 5; ++k) vA[k] = base4[min(k * 256 + tid, maxflat)];
    #pragma unroll
    for (int k = 0; k < 5; ++k) vB[k] = base4[min((5 + k) * 256 + tid, maxflat)];
    __builtin_amdgcn_sched_barrier(0);   // pin the loads above the IoU loop

    float reg_sum = 0.0f;
    int pos_cnt = 0;
    int code = -2;

    if (a < AA) {
        const float4 an = ((const float4*)anchors)[a];
        const float ax1 = an.x, ay1 = an.y, ax2 = an.z, ay2 = an.w;
        // exact IEEE ops (no FMA contraction) so pos/ignore thresholds match numpy bit-for-bit:
        const float area_a = __fmul_rn(__fsub_rn(ax2, ax1), __fsub_rn(ay2, ay1));

        float best_iou = -1.0f;
        int best = 0;
        #pragma unroll
        for (int j = 0; j < MM; ++j) {
            const float bx1 = ann[j * 5 + 0];
            const float by1 = ann[j * 5 + 1];
            const float bx2 = ann[j * 5 + 2];
            const float by2 = ann[j * 5 + 3];
            const float ix1 = fmaxf(ax1, bx1);
            const float iy1 = fmaxf(ay1, by1);
            const float ix2 = fminf(ax2, bx2);
            const float iy2 = fminf(ay2, by2);
            const float iw = fmaxf(__fsub_rn(ix2, ix1), 0.0f);
            const float ih = fmaxf(__fsub_rn(iy2, iy1), 0.0f);
            const float inter = __fmul_rn(iw, ih);
            const float uni = __fsub_rn(__fadd_rn(area_a, areab[j]), inter);
            const float iou = __fdiv_rn(inter, fmaxf(uni, 1e-8f));
            if (iou > best_iou) { best_iou = iou; best = j; }  // strict > keeps first max (argmax)
        }

        const bool pos = best_iou >= 0.5f;
        const bool ign = (best_iou > 0.4f) && !pos;
        const float cx = (ax1 + ax2) * 0.5f;
        const float cy = (ay1 + ay2) * 0.5f;
        const bool inside = (cx >= 0.0f) && (cx < 800.0f) && (cy >= 0.0f) && (cy < 800.0f);

        const bool valid = inside && !ign;      // state != -1
        if (valid) code = pos ? (int)ann[best * 5 + 4] : -1;

        if (pos && inside) {                    // state == 1
            pos_cnt = 1;
            const float aw = ax2 - ax1;
            const float ah = ay2 - ay1;
            const float bx1 = ann[best * 5 + 0];
            const float by1 = ann[best * 5 + 1];
            const float bx2 = ann[best * 5 + 2];
            const float by2 = ann[best * 5 + 3];
            float t[4];
            t[0] = ((bx1 - ax1) / aw) / 0.2f;
            t[1] = ((by1 - ay1) / ah) / 0.2f;
            t[2] = ((bx2 - ax2) / aw) / 0.2f;
            t[3] = ((by2 - ay2) / ah) / 0.2f;
            const float* rg = regression + (((size_t)b * AA + a) * 4);
            #pragma unroll
            for (int k = 0; k < 4; ++k) {
                const float d = fabsf(rg[k] - t[k]);
                reg_sum += (d < (1.0f / 9.0f)) ? (4.5f * d * d) : (d - (0.5f / 9.0f));
            }
        }
    }
    scode[tid] = code;
    __syncthreads();

    // ---- focal phase: software-pipelined. Batches 0/1 already in registers;
    // issue batch 2 now, batch 3 after batch-0 math, so the stream never
    // drains while the log-heavy VALU work runs. Processing order (0,1,2,3)
    // and all arithmetic identical to baseline -> bitwise-identical csum.
    float csum = 0.0f;

    float4 vC[5];
    #pragma unroll
    for (int k = 0; k < 5; ++k) vC[k] = base4[min((10 + k) * 256 + tid, maxflat)];

    FOCAL_BATCH(vA, 0)

    float4 vD[5];
    #pragma unroll
    for (int k = 0; k < 5; ++k) vD[k] = base4[min((15 + k) * 256 + tid, maxflat)];

    FOCAL_BATCH(vB, 1)
    FOCAL_BATCH(vC, 2)
    FOCAL_BATCH(vD, 3)

    // ---- block reduction (wave shuffle + LDS), plain stores, no atomics ----
    #pragma unroll
    for (int off = 32; off > 0; off >>= 1) {
        csum    += __shfl_down(csum, off);
        reg_sum += __shfl_down(reg_sum, off);
        pos_cnt += __shfl_down(pos_cnt, off);
    }
    __shared__ float wc[4], wr[4];
    __shared__ int   wp[4];
    const int wave = tid >> 6, lane = tid & 63;
    if (lane == 0) { wc[wave] = csum; wr[wave] = reg_sum; wp[wave] = pos_cnt; }
    __syncthreads();
    if (tid == 0) {
        const int idx = b * GX + blockIdx.x;
        cls_part[idx] = wc[0] + wc[1] + wc[2] + wc[3];
        reg_part[idx] = wr[0] + wr[1] + wr[2] + wr[3];
        pos_part[idx] = (unsigned)(wp[0] + wp[1] + wp[2] + wp[3]);
    }
}

__global__ __launch_bounds__(256) void finalize_kernel(
    const float* __restrict__ cls_part,
    const float* __restrict__ reg_part,
    const unsigned* __restrict__ pos_part,
    float* __restrict__ out)
{
    float cs = 0.0f, rs = 0.0f;
    unsigned pc = 0;
    for (int i = threadIdx.x; i < NBLK; i += 256) {
        cs += cls_part[i];
        rs += reg_part[i];
        pc += pos_part[i];
    }
    #pragma unroll
    for (int off = 32; off > 0; off >>= 1) {
        cs += __shfl_down(cs, off);
        rs += __shfl_down(rs, off);
        pc += __shfl_down(pc, off);
    }
    __shared__ float wc[4], wr[4];
    __shared__ unsigned wp[4];
    const int wave = threadIdx.x >> 6, lane = threadIdx.x & 63;
    if (lane == 0) { wc[wave] = cs; wr[wave] = rs; wp[wave] = pc; }
    __syncthreads();
    if (threadIdx.x == 0) {
        const float csum = wc[0] + wc[1] + wc[2] + wc[3];
        const float rsum = wr[0] + wr[1] + wr[2] + wr[3];
        const float np = fmaxf((float)(wp[0] + wp[1] + wp[2] + wp[3]), 1.0f);
        out[0] = (csum + rsum) / np;
    }
}

extern "C" void kernel_launch(void* const* d_in, const int* in_sizes, int n_in,
                              void* d_out, int out_size, void* d_ws, size_t ws_size,
                              hipStream_t stream)
{
    const float* classification = (const float*)d_in[0];  // BB*AA*NC
    const float* regression     = (const float*)d_in[1];  // BB*AA*4
    const float* anchors        = (const float*)d_in[2];  // AA*4
    const float* annotations    = (const float*)d_in[3];  // BB*MM*5
    float* out = (float*)d_out;

    float*    cls_part = (float*)d_ws;
    float*    reg_part = cls_part + NBLK;
    unsigned* pos_part = (unsigned*)(reg_part + NBLK);

    dim3 grid(GX, BB);
    fused_kernel<<<grid, 256, 0, stream>>>(anchors, annotations, regression,
                                           classification, cls_part, reg_part, pos_part);
    finalize_kernel<<<1, 256, 0, stream>>>(cls_part, reg_part, pos_part, out);
}

// Round 2
// 196.752 us; speedup vs baseline: 1.0658x; 1.0658x over previous
//
#include <hip/hip_runtime.h>

#define BB 4
#define AA 100000
#define MM 32
#define NC 80
#define GX 391               // ceil(AA/256)
#define NBLK (GX * BB)       // 1564 blocks

// ws layout (floats): cls_part[NBLK] | reg_part[NBLK] | pos_part[NBLK] (as uint)
// All partials written unconditionally by every block -> no zero-init, no atomics.

// Async global->LDS, 16B per lane, zero VGPR cost for the payload.
__device__ __forceinline__ void gld_lds16(const float4* g, float4* l) {
    __builtin_amdgcn_global_load_lds(
        (const __attribute__((address_space(1))) void*)g,
        (__attribute__((address_space(3))) void*)l,
        16, 0, 0);
}

// ---- focal math for one float4 (4 classes), arithmetic identical to baseline ----
// labeled-column pick via explicit select tree (no runtime-indexed array -> no scratch).
#define FOCAL_K(vk, flatk)                                                  \
  {                                                                         \
    const int s    = (flatk) / 20;                                          \
    const int colb = ((flatk) - s * 20) * 4;                                \
    const int c    = scode[s];                                              \
    const float m  = (c != -2) ? 1.0f : 0.0f;                               \
    const float q0 = fminf(fmaxf((vk).x, 1e-4f), 0.9999f);                  \
    const float q1 = fminf(fmaxf((vk).y, 1e-4f), 0.9999f);                  \
    const float q2 = fminf(fmaxf((vk).z, 1e-4f), 0.9999f);                  \
    const float q3 = fminf(fmaxf((vk).w, 1e-4f), 0.9999f);                  \
    float sub = 0.0f;                                                       \
    sub += 0.75f * q0 * q0 * (-__logf(1.0f - q0));                          \
    sub += 0.75f * q1 * q1 * (-__logf(1.0f - q1));                          \
    sub += 0.75f * q2 * q2 * (-__logf(1.0f - q2));                          \
    sub += 0.75f * q3 * q3 * (-__logf(1.0f - q3));                          \
    csum += m * sub;                                                        \
    const unsigned rel = (unsigned)(c - colb);                              \
    if (rel < 4u) {  /* rare: the labeled column lands in this float4 */    \
      const float p = (rel & 2u) ? ((rel & 1u) ? q3 : q2)                   \
                                 : ((rel & 1u) ? q1 : q0);                  \
      const float onem = 1.0f - p;                                          \
      csum += 0.25f * onem * onem * (-__logf(p))                            \
            - 0.75f * p * p * (-__logf(onem));                              \
    }                                                                       \
  }

#define FOCAL_BATCH(vv, batch)                                              \
  _Pragma("unroll")                                                         \
  for (int k = 0; k < 5; ++k) {                                             \
    const int flat = ((batch) * 5 + k) * 256 + tid;                         \
    FOCAL_K((vv)[k], flat)                                                  \
  }

__global__ __launch_bounds__(256) void fused_kernel(
    const float* __restrict__ anchors,      // AA*4
    const float* __restrict__ annotations,  // BB*MM*5
    const float* __restrict__ regression,   // BB*AA*4
    const float* __restrict__ cls,          // BB*AA*NC, read as float4
    float* __restrict__ cls_part,
    float* __restrict__ reg_part,
    unsigned* __restrict__ pos_part)
{
    __shared__ float ann[MM * 5];
    __shared__ float areab[MM];
    __shared__ int scode[256];      // -2 = excluded/fake, -1 = valid negative, 0..79 = positive class
    __shared__ float4 pre[5 * 256]; // 20 KB: batch 0 of the cls stream, DMA'd under the IoU phase
    const int b = blockIdx.y;
    const int tid = threadIdx.x;
    if (tid < MM * 5) ann[tid] = annotations[b * MM * 5 + tid];
    if (tid < MM) {
        // same __fsub_rn/__fmul_rn ops as the per-anchor version -> identical bits
        const float bx1 = annotations[b * MM * 5 + tid * 5 + 0];
        const float by1 = annotations[b * MM * 5 + tid * 5 + 1];
        const float bx2 = annotations[b * MM * 5 + tid * 5 + 2];
        const float by2 = annotations[b * MM * 5 + tid * 5 + 3];
        areab[tid] = __fmul_rn(__fsub_rn(bx2, bx1), __fsub_rn(by2, by1));
    }
    __syncthreads();

    const int abase = blockIdx.x * 256;
    const int a = abase + tid;
    const float4* base4 = (const float4*)cls + ((size_t)b * AA + abase) * 20;
    const int maxflat = (abase + 256 <= AA) ? (5120 - 1) : ((AA - abase) * 20 - 1);

    // Anchor load FIRST (so its waitcnt is vmcnt(5): prefetch stays in flight).
    float4 an = make_float4(0.f, 0.f, 0.f, 0.f);
    if (a < AA) an = ((const float4*)anchors)[a];

    // ---- async prefetch of focal batch 0 into LDS: zero VGPRs, rides out
    // under the compute-only IoU loop. The scode __syncthreads() below drains
    // vmcnt(0), so pre[] is guaranteed resident when the focal phase starts.
    #pragma unroll
    for (int k = 0; k < 5; ++k)
        gld_lds16(&base4[min(k * 256 + tid, maxflat)], &pre[k * 256 + tid]);

    float reg_sum = 0.0f;
    int pos_cnt = 0;
    int code = -2;

    if (a < AA) {
        const float ax1 = an.x, ay1 = an.y, ax2 = an.z, ay2 = an.w;
        // exact IEEE ops (no FMA contraction) so pos/ignore thresholds match numpy bit-for-bit:
        const float area_a = __fmul_rn(__fsub_rn(ax2, ax1), __fsub_rn(ay2, ay1));

        float best_iou = -1.0f;
        int best = 0;
        #pragma unroll
        for (int j = 0; j < MM; ++j) {
            const float bx1 = ann[j * 5 + 0];
            const float by1 = ann[j * 5 + 1];
            const float bx2 = ann[j * 5 + 2];
            const float by2 = ann[j * 5 + 3];
            const float ix1 = fmaxf(ax1, bx1);
            const float iy1 = fmaxf(ay1, by1);
            const float ix2 = fminf(ax2, bx2);
            const float iy2 = fminf(ay2, by2);
            const float iw = fmaxf(__fsub_rn(ix2, ix1), 0.0f);
            const float ih = fmaxf(__fsub_rn(iy2, iy1), 0.0f);
            const float inter = __fmul_rn(iw, ih);
            const float uni = __fsub_rn(__fadd_rn(area_a, areab[j]), inter);
            const float iou = __fdiv_rn(inter, fmaxf(uni, 1e-8f));
            if (iou > best_iou) { best_iou = iou; best = j; }  // strict > keeps first max (argmax)
        }

        const bool pos = best_iou >= 0.5f;
        const bool ign = (best_iou > 0.4f) && !pos;
        const float cx = (ax1 + ax2) * 0.5f;
        const float cy = (ay1 + ay2) * 0.5f;
        const bool inside = (cx >= 0.0f) && (cx < 800.0f) && (cy >= 0.0f) && (cy < 800.0f);

        const bool valid = inside && !ign;      // state != -1
        if (valid) code = pos ? (int)ann[best * 5 + 4] : -1;

        if (pos && inside) {                    // state == 1
            pos_cnt = 1;
            const float aw = ax2 - ax1;
            const float ah = ay2 - ay1;
            const float bx1 = ann[best * 5 + 0];
            const float by1 = ann[best * 5 + 1];
            const float bx2 = ann[best * 5 + 2];
            const float by2 = ann[best * 5 + 3];
            float t[4];
            t[0] = ((bx1 - ax1) / aw) / 0.2f;
            t[1] = ((by1 - ay1) / ah) / 0.2f;
            t[2] = ((bx2 - ax2) / aw) / 0.2f;
            t[3] = ((by2 - ay2) / ah) / 0.2f;
            const float* rg = regression + (((size_t)b * AA + a) * 4);
            #pragma unroll
            for (int k = 0; k < 4; ++k) {
                const float d = fabsf(rg[k] - t[k]);
                reg_sum += (d < (1.0f / 9.0f)) ? (4.5f * d * d) : (d - (0.5f / 9.0f));
            }
        }
    }
    scode[tid] = code;
    __syncthreads();   // publishes scode AND drains vmcnt(0) -> pre[] ready

    // ---- focal phase: batch 0 comes from LDS (already resident). Issue batch
    // 1's global loads first so the HBM stream never drains; then the rolling
    // load->process pipeline continues for batches 2-3. Processing order
    // (0,1,2,3) and all arithmetic identical to baseline -> bitwise-identical csum.
    float csum = 0.0f;

    float4 v1[5];
    #pragma unroll
    for (int k = 0; k < 5; ++k) v1[k] = base4[min((5 + k) * 256 + tid, maxflat)];

    float4 v0[5];
    #pragma unroll
    for (int k = 0; k < 5; ++k) v0[k] = pre[k * 256 + tid];
    FOCAL_BATCH(v0, 0)

    float4 v2[5];
    #pragma unroll
    for (int k = 0; k < 5; ++k) v2[k] = base4[min((10 + k) * 256 + tid, maxflat)];
    FOCAL_BATCH(v1, 1)

    float4 v3[5];
    #pragma unroll
    for (int k = 0; k < 5; ++k) v3[k] = base4[min((15 + k) * 256 + tid, maxflat)];
    FOCAL_BATCH(v2, 2)
    FOCAL_BATCH(v3, 3)

    // ---- block reduction (wave shuffle + LDS), plain stores, no atomics ----
    #pragma unroll
    for (int off = 32; off > 0; off >>= 1) {
        csum    += __shfl_down(csum, off);
        reg_sum += __shfl_down(reg_sum, off);
        pos_cnt += __shfl_down(pos_cnt, off);
    }
    __shared__ float wc[4], wr[4];
    __shared__ int   wp[4];
    const int wave = tid >> 6, lane = tid & 63;
    if (lane == 0) { wc[wave] = csum; wr[wave] = reg_sum; wp[wave] = pos_cnt; }
    __syncthreads();
    if (tid == 0) {
        const int idx = b * GX + blockIdx.x;
        cls_part[idx] = wc[0] + wc[1] + wc[2] + wc[3];
        reg_part[idx] = wr[0] + wr[1] + wr[2] + wr[3];
        pos_part[idx] = (unsigned)(wp[0] + wp[1] + wp[2] + wp[3]);
    }
}

__global__ __launch_bounds__(256) void finalize_kernel(
    const float* __restrict__ cls_part,
    const float* __restrict__ reg_part,
    const unsigned* __restrict__ pos_part,
    float* __restrict__ out)
{
    float cs = 0.0f, rs = 0.0f;
    unsigned pc = 0;
    for (int i = threadIdx.x; i < NBLK; i += 256) {
        cs += cls_part[i];
        rs += reg_part[i];
        pc += pos_part[i];
    }
    #pragma unroll
    for (int off = 32; off > 0; off >>= 1) {
        cs += __shfl_down(cs, off);
        rs += __shfl_down(rs, off);
        pc += __shfl_down(pc, off);
    }
    __shared__ float wc[4], wr[4];
    __shared__ unsigned wp[4];
    const int wave = threadIdx.x >> 6, lane = threadIdx.x & 63;
    if (lane == 0) { wc[wave] = cs; wr[wave] = rs; wp[wave] = pc; }
    __syncthreads();
    if (threadIdx.x == 0) {
        const float csum = wc[0] + wc[1] + wc[2] + wc[3];
        const float rsum = wr[0] + wr[1] + wr[2] + wr[3];
        const float np = fmaxf((float)(wp[0] + wp[1] + wp[2] + wp[3]), 1.0f);
        out[0] = (csum + rsum) / np;
    }
}

extern "C" void kernel_launch(void* const* d_in, const int* in_sizes, int n_in,
                              void* d_out, int out_size, void* d_ws, size_t ws_size,
                              hipStream_t stream)
{
    const float* classification = (const float*)d_in[0];  // BB*AA*NC
    const float* regression     = (const float*)d_in[1];  // BB*AA*4
    const float* anchors        = (const float*)d_in[2];  // AA*4
    const float* annotations    = (const float*)d_in[3];  // BB*MM*5
    float* out = (float*)d_out;

    float*    cls_part = (float*)d_ws;
    float*    reg_part = cls_part + NBLK;
    unsigned* pos_part = (unsigned*)(reg_part + NBLK);

    dim3 grid(GX, BB);
    fused_kernel<<<grid, 256, 0, stream>>>(anchors, annotations, regression,
                                           classification, cls_part, reg_part, pos_part);
    finalize_kernel<<<1, 256, 0, stream>>>(cls_part, reg_part, pos_part, out);
}